// Round 7
// baseline (296.608 us; speedup 1.0000x reference)
//
#include <hip/hip_runtime.h>
#include <hip/hip_bf16.h>

// Sizes
constexpr int BATCH = 8192;
constexpr int NREAL = 2000;   // real feature / output-col count
constexpr int KSLOT = 2048;   // per-matrix padded K slot
constexpr int KPAD  = 6144;   // 3 * 2048
constexpr int NPAD  = 2048;   // padded N (W_cat rows)
constexpr int NT    = KPAD / 64;  // 96 K-tiles of 64

typedef short bf16x8 __attribute__((ext_vector_type(8)));
typedef float f32x4  __attribute__((ext_vector_type(4)));

__device__ inline void gload_lds16(const void* g, void* l) {
  __builtin_amdgcn_global_load_lds(
      (const __attribute__((address_space(1))) unsigned int*)g,
      (__attribute__((address_space(3))) unsigned int*)l,
      16, 0, 0);
}

__device__ inline unsigned short f2bf(float x) {
  union { float f; unsigned int u; } v;
  v.f = x;
  unsigned int r = v.u + 0x7fffu + ((v.u >> 16) & 1u);
  return (unsigned short)(r >> 16);
}

// ---------------------------------------------------------------------------
// Kernel 1: fused pack. blockIdx.x < 8192: standardize (ddof=1) activations
// into A_cat [8192][6144]; else weight-concat rows into W_cat [2048][6144].
// grid (8192+2048, 3), block 256.
// ---------------------------------------------------------------------------
__global__ __launch_bounds__(256) void pack_kernel(
    const float* __restrict__ prev, const float* __restrict__ nxt,
    const float* __restrict__ selfa,
    const float* __restrict__ fW, const float* __restrict__ bW,
    const float* __restrict__ lW,
    unsigned short* __restrict__ Acat, unsigned short* __restrict__ Wcat) {
  const int mat = blockIdx.y;
  const int t = threadIdx.x;

  if (blockIdx.x >= BATCH) {
    // ---- weight pack ----
    const int s = blockIdx.x - BATCH;
    uint4 q = make_uint4(0, 0, 0, 0);
    if (s < NREAL && t < 250) {
      const float* src = ((mat == 0) ? fW : (mat == 1) ? bW : lW) +
                         (size_t)s * NREAL + t * 8;
      const float4* p = (const float4*)src;
      float4 a = p[0], b = p[1];
      q.x = (unsigned)f2bf(a.x) | ((unsigned)f2bf(a.y) << 16);
      q.y = (unsigned)f2bf(a.z) | ((unsigned)f2bf(a.w) << 16);
      q.z = (unsigned)f2bf(b.x) | ((unsigned)f2bf(b.y) << 16);
      q.w = (unsigned)f2bf(b.z) | ((unsigned)f2bf(b.w) << 16);
    }
    *(uint4*)(Wcat + (size_t)s * KPAD + mat * KSLOT + t * 8) = q;
    return;
  }

  // ---- standardize pack ----
  __shared__ float red[4];
  const int row = blockIdx.x;
  const float* src = (mat == 0) ? prev : (mat == 1) ? nxt : selfa;

  float x[8];
  float s1 = 0.f;
  if (t < 250) {
    const float4* p = (const float4*)(src + (size_t)row * NREAL + t * 8);
    float4 a = p[0], b = p[1];
    x[0] = a.x; x[1] = a.y; x[2] = a.z; x[3] = a.w;
    x[4] = b.x; x[5] = b.y; x[6] = b.z; x[7] = b.w;
#pragma unroll
    for (int j = 0; j < 8; ++j) s1 += x[j];
  } else {
#pragma unroll
    for (int j = 0; j < 8; ++j) x[j] = 0.f;
  }
#pragma unroll
  for (int o = 32; o; o >>= 1) s1 += __shfl_xor(s1, o);
  if ((t & 63) == 0) red[t >> 6] = s1;
  __syncthreads();
  const float mean = (red[0] + red[1] + red[2] + red[3]) * (1.f / 2000.f);
  __syncthreads();

  float ss = 0.f;
  if (t < 250) {
#pragma unroll
    for (int j = 0; j < 8; ++j) { float d = x[j] - mean; ss += d * d; }
  }
#pragma unroll
  for (int o = 32; o; o >>= 1) ss += __shfl_xor(ss, o);
  if ((t & 63) == 0) red[t >> 6] = ss;
  __syncthreads();
  const float var = (red[0] + red[1] + red[2] + red[3]) * (1.f / 1999.f);
  const float scale = 1.f / (sqrtf(var) + 1e-8f);

  unsigned short o8[8];
  if (t < 250) {
#pragma unroll
    for (int j = 0; j < 8; ++j) o8[j] = f2bf((x[j] - mean) * scale);
  } else {
#pragma unroll
    for (int j = 0; j < 8; ++j) o8[j] = 0;
  }
  uint4 q;
  q.x = (unsigned)o8[0] | ((unsigned)o8[1] << 16);
  q.y = (unsigned)o8[2] | ((unsigned)o8[3] << 16);
  q.z = (unsigned)o8[4] | ((unsigned)o8[5] << 16);
  q.w = (unsigned)o8[6] | ((unsigned)o8[7] << 16);
  *(uint4*)(Acat + (size_t)row * KPAD + mat * KSLOT + t * 8) = q;
}

// ---------------------------------------------------------------------------
// Kernel 2: 256x256 bf16 MFMA GEMM, BK=64, **4 waves (2Mx2N), 128x128/wave**.
// Rationale: 8-wave/128x64 geometry is LDS-read-bound (2816 cy LDS vs 2064 cy
// MFMA per tile per CU at 12cy/b128); 128x128/wave cuts LDS reads 1.5x ->
// 1024 cy LDS vs 1032 cy MFMA (balanced). acc 256 f32/lane (1 wave/SIMD).
// 2 phases/tile: af read one phase ahead (ping-pong), bf same-phase with
// fn-outer MFMA; stage one half (A+B, 8 gloads) per phase; uniform vmcnt(8)
// forcing loads issued 2 phases back. 2 barriers/tile. XOR-swizzled chunks.
// grid 256 (= 32 bm x 8 bn), block 256.
// ---------------------------------------------------------------------------
__global__ __launch_bounds__(256, 1) void gemm_kernel(
    const unsigned short* __restrict__ A,   // [8192][6144] bf16
    const unsigned short* __restrict__ W,   // [2048][6144] bf16
    const float* __restrict__ fb, const float* __restrict__ bb,
    const float* __restrict__ lb,
    const float* __restrict__ selfact,      // [8192][2000] f32
    float* __restrict__ out) {              // [8192][2000] f32
  __shared__ unsigned short lds[2][2][2][256][32];  // [buf][mat][h] 128 KiB
  unsigned short* ldsF = &lds[0][0][0][0][0];

  const int tid  = threadIdx.x;
  const int wave = tid >> 6;
  const int lane = tid & 63;
  const int wm = wave >> 1;     // 0..1
  const int wn = wave & 1;      // 0..1

  // XCD-aware block swizzle (256 blocks, 8 XCDs, 32/XCD, 4 bm-panels each)
  const int nbid = (blockIdx.x & 7) * 32 + (blockIdx.x >> 3);
  const int bm = nbid >> 3;     // 0..31
  const int bn = nbid & 7;      // 0..7

  // staging per-thread source (inverse swizzle): row=tid>>2 (0..63), chunk
  const int srow = tid >> 2;
  const int sc = (tid & 3) ^ ((tid >> 3) & 3);   // (tid&3) ^ ((row>>1)&3)
  const unsigned short* Asrc =
      A + (size_t)(bm * 256 + srow) * KPAD + sc * 8;
  const unsigned short* Bsrc =
      W + (size_t)(bn * 256 + srow) * KPAD + sc * 8;

  // fragment read bases (swizzle folds to per-lane constant)
  const int pcx = (lane >> 4) ^ ((lane >> 1) & 3);
  const unsigned short* aF = ldsF + (wm * 128 + (lane & 15)) * 32 + pcx * 8;
  const unsigned short* bF = ldsF + (wn * 128 + (lane & 15)) * 32 + pcx * 8;

  f32x4 acc[8][8] = {};
  bf16x8 afA[8], afB[8], bfr[8];

  // one half = A[256][32] (16KB, 4 calls) + B[256][32] (16KB, 4 calls)
#define STAGE_H(sb, h, tt) { \
    const unsigned short* gA_ = Asrc + (size_t)(tt) * 64 + (h) * 32; \
    const unsigned short* gB_ = Bsrc + (size_t)(tt) * 64 + (h) * 32; \
    unsigned short* dA_ = ldsF + ((sb) * 4 + (h)) * 8192 + wave * 512; \
    unsigned short* dB_ = ldsF + ((sb) * 4 + 2 + (h)) * 8192 + wave * 512; \
    gload_lds16(gA_, dA_); \
    gload_lds16(gA_ + (size_t)64 * KPAD, dA_ + 2048); \
    gload_lds16(gA_ + (size_t)128 * KPAD, dA_ + 4096); \
    gload_lds16(gA_ + (size_t)192 * KPAD, dA_ + 6144); \
    gload_lds16(gB_, dB_); \
    gload_lds16(gB_ + (size_t)64 * KPAD, dB_ + 2048); \
    gload_lds16(gB_ + (size_t)128 * KPAD, dB_ + 4096); \
    gload_lds16(gB_ + (size_t)192 * KPAD, dB_ + 6144); \
  }

#define READ_BF(b, kk) \
    _Pragma("unroll") for (int fn = 0; fn < 8; ++fn) \
      bfr[fn] = *(const bf16x8*)(bF + ((b) * 4 + 2 + (kk)) * 8192 + fn * 512);

#define READ_AF(dst, b, kk) \
    _Pragma("unroll") for (int fm = 0; fm < 8; ++fm) \
      dst[fm] = *(const bf16x8*)(aF + ((b) * 4 + (kk)) * 8192 + fm * 512);

  // fn-outer: first MFMA gated only by bfr[0] (af set read last phase)
#define MFMA64(afr) \
    _Pragma("unroll") for (int fn = 0; fn < 8; ++fn) \
    _Pragma("unroll") for (int fm = 0; fm < 8; ++fm) \
      acc[fm][fn] = __builtin_amdgcn_mfma_f32_16x16x32_bf16( \
          afr[fm], bfr[fn], acc[fm][fn], 0, 0, 0);

  // phA(t): consume (t,kk0) via afA; read bf(t,kk0) + afB<-(t,kk1);
  //         stage t+1 h1. vmcnt(8) forces t h1 (issued 2 phases back).
#define PHA(b, t, DS, VM) { \
    asm volatile("s_waitcnt vmcnt(" VM ")" ::: "memory"); \
    __builtin_amdgcn_s_barrier(); \
    __builtin_amdgcn_sched_barrier(0); \
    READ_BF(b, 0) \
    READ_AF(afB, b, 1) \
    if (DS) STAGE_H((b) ^ 1, 1, (t) + 1) \
    MFMA64(afA) \
  }
  // phB(t): consume (t,kk1) via afB; read bf(t,kk1) + afA<-(t+1,kk0);
  //         stage t+2 h0. vmcnt(8) forces t+1 h0 (issued 2 phases back).
#define PHB(b, t, DS, RA, VM) { \
    asm volatile("s_waitcnt vmcnt(" VM ")" ::: "memory"); \
    __builtin_amdgcn_s_barrier(); \
    __builtin_amdgcn_sched_barrier(0); \
    READ_BF(b, 1) \
    if (RA) READ_AF(afA, (b) ^ 1, 0) \
    if (DS) STAGE_H(b, 0, (t) + 2) \
    MFMA64(afB) \
  }

  // Prologue: stage t0 h0, t0 h1, t1 h0 (24 loads pending).
  STAGE_H(0, 0, 0)
  STAGE_H(0, 1, 0)
  STAGE_H(1, 0, 1)
  asm volatile("s_waitcnt vmcnt(16)" ::: "memory");  // t0 h0 landed
  __builtin_amdgcn_s_barrier();
  __builtin_amdgcn_sched_barrier(0);
  READ_AF(afA, 0, 0)

  for (int t = 0; t < NT - 2; ++t) {
    const int b = t & 1;
    PHA(b, t, true, "8")
    PHB(b, t, true, true, "8")
  }
  // t = NT-2 (b=0): stage only NT-1 h1; still read ahead afA(NT-1, kk0).
  PHA(0, NT - 2, true, "8")
  PHB(0, NT - 2, false, true, "8")
  // t = NT-1 (b=1): drain.
  PHA(1, NT - 1, false, "0")
  PHB(1, NT - 1, false, false, "0")

  // Epilogue: C/D layout col=lane&15, row=(lane>>4)*4+reg
  const int colLane = lane & 15;
  const int rowGrp  = (lane >> 4) * 4;
#pragma unroll
  for (int fn = 0; fn < 8; ++fn) {
    const int col = bn * 256 + wn * 128 + fn * 16 + colLane;
    if (col < NREAL) {
      const float bias = fb[col] + bb[col] + lb[col];
#pragma unroll
      for (int fm = 0; fm < 8; ++fm) {
        const int row0 = bm * 256 + wm * 128 + fm * 16 + rowGrp;
#pragma unroll
        for (int r = 0; r < 4; ++r) {
          const float pre = acc[fm][fn][r] + bias;
          const size_t oi = (size_t)(row0 + r) * NREAL + col;
          out[oi] = 0.7f * fmaxf(pre, 0.f) + 0.3f * selfact[oi];
        }
      }
    }
  }
#undef PHB
#undef PHA
#undef MFMA64
#undef READ_AF
#undef READ_BF
#undef STAGE_H
}

// ---------------------------------------------------------------------------
extern "C" void kernel_launch(void* const* d_in, const int* in_sizes, int n_in,
                              void* d_out, int out_size, void* d_ws,
                              size_t ws_size, hipStream_t stream) {
  const float* prev = (const float*)d_in[0];
  const float* selfa = (const float*)d_in[1];
  const float* nxt  = (const float*)d_in[2];
  const float* fW = (const float*)d_in[3];
  const float* fb = (const float*)d_in[4];
  const float* bW = (const float*)d_in[5];
  const float* bb = (const float*)d_in[6];
  const float* lW = (const float*)d_in[7];
  const float* lb = (const float*)d_in[8];
  float* out = (float*)d_out;

  unsigned short* Acat = (unsigned short*)d_ws;                 // 100.7 MB
  unsigned short* Wcat = Acat + (size_t)BATCH * KPAD;           // +25.2 MB

  pack_kernel<<<dim3(BATCH + NPAD, 3), 256, 0, stream>>>(
      prev, nxt, selfa, fW, bW, lW, Acat, Wcat);
  gemm_kernel<<<dim3(32 * 8), 256, 0, stream>>>(Acat, Wcat, fb, bb, lb,
                                                selfa, out);
}

// Round 8
// 262.602 us; speedup vs baseline: 1.1295x; 1.1295x over previous
//
#include <hip/hip_runtime.h>
#include <hip/hip_bf16.h>

// Sizes
constexpr int BATCH = 8192;
constexpr int NREAL = 2000;   // real feature / output-col count
constexpr int KSLOT = 2048;   // per-matrix padded K slot
constexpr int KPAD  = 6144;   // 3 * 2048
constexpr int NPAD  = 2048;   // padded N (W_cat rows)
constexpr int NT    = KPAD / 64;  // 96 K-tiles of 64

typedef short bf16x8 __attribute__((ext_vector_type(8)));
typedef float f32x4  __attribute__((ext_vector_type(4)));

__device__ inline void gload_lds16(const void* g, void* l) {
  __builtin_amdgcn_global_load_lds(
      (const __attribute__((address_space(1))) unsigned int*)g,
      (__attribute__((address_space(3))) unsigned int*)l,
      16, 0, 0);
}

__device__ inline unsigned short f2bf(float x) {
  union { float f; unsigned int u; } v;
  v.f = x;
  unsigned int r = v.u + 0x7fffu + ((v.u >> 16) & 1u);
  return (unsigned short)(r >> 16);
}

// ---------------------------------------------------------------------------
// Kernel 1: fused pack. blockIdx.x < 8192: standardize (ddof=1) activations
// into A_cat [8192][6144]; else weight-concat rows into W_cat [2048][6144].
// grid (8192+2048, 3), block 256.
// ---------------------------------------------------------------------------
__global__ __launch_bounds__(256) void pack_kernel(
    const float* __restrict__ prev, const float* __restrict__ nxt,
    const float* __restrict__ selfa,
    const float* __restrict__ fW, const float* __restrict__ bW,
    const float* __restrict__ lW,
    unsigned short* __restrict__ Acat, unsigned short* __restrict__ Wcat) {
  const int mat = blockIdx.y;
  const int t = threadIdx.x;

  if (blockIdx.x >= BATCH) {
    // ---- weight pack ----
    const int s = blockIdx.x - BATCH;
    uint4 q = make_uint4(0, 0, 0, 0);
    if (s < NREAL && t < 250) {
      const float* src = ((mat == 0) ? fW : (mat == 1) ? bW : lW) +
                         (size_t)s * NREAL + t * 8;
      const float4* p = (const float4*)src;
      float4 a = p[0], b = p[1];
      q.x = (unsigned)f2bf(a.x) | ((unsigned)f2bf(a.y) << 16);
      q.y = (unsigned)f2bf(a.z) | ((unsigned)f2bf(a.w) << 16);
      q.z = (unsigned)f2bf(b.x) | ((unsigned)f2bf(b.y) << 16);
      q.w = (unsigned)f2bf(b.z) | ((unsigned)f2bf(b.w) << 16);
    }
    *(uint4*)(Wcat + (size_t)s * KPAD + mat * KSLOT + t * 8) = q;
    return;
  }

  // ---- standardize pack ----
  __shared__ float red[4];
  const int row = blockIdx.x;
  const float* src = (mat == 0) ? prev : (mat == 1) ? nxt : selfa;

  float x[8];
  float s1 = 0.f;
  if (t < 250) {
    const float4* p = (const float4*)(src + (size_t)row * NREAL + t * 8);
    float4 a = p[0], b = p[1];
    x[0] = a.x; x[1] = a.y; x[2] = a.z; x[3] = a.w;
    x[4] = b.x; x[5] = b.y; x[6] = b.z; x[7] = b.w;
#pragma unroll
    for (int j = 0; j < 8; ++j) s1 += x[j];
  } else {
#pragma unroll
    for (int j = 0; j < 8; ++j) x[j] = 0.f;
  }
#pragma unroll
  for (int o = 32; o; o >>= 1) s1 += __shfl_xor(s1, o);
  if ((t & 63) == 0) red[t >> 6] = s1;
  __syncthreads();
  const float mean = (red[0] + red[1] + red[2] + red[3]) * (1.f / 2000.f);
  __syncthreads();

  float ss = 0.f;
  if (t < 250) {
#pragma unroll
    for (int j = 0; j < 8; ++j) { float d = x[j] - mean; ss += d * d; }
  }
#pragma unroll
  for (int o = 32; o; o >>= 1) ss += __shfl_xor(ss, o);
  if ((t & 63) == 0) red[t >> 6] = ss;
  __syncthreads();
  const float var = (red[0] + red[1] + red[2] + red[3]) * (1.f / 1999.f);
  const float scale = 1.f / (sqrtf(var) + 1e-8f);

  unsigned short o8[8];
  if (t < 250) {
#pragma unroll
    for (int j = 0; j < 8; ++j) o8[j] = f2bf((x[j] - mean) * scale);
  } else {
#pragma unroll
    for (int j = 0; j < 8; ++j) o8[j] = 0;
  }
  uint4 q;
  q.x = (unsigned)o8[0] | ((unsigned)o8[1] << 16);
  q.y = (unsigned)o8[2] | ((unsigned)o8[3] << 16);
  q.z = (unsigned)o8[4] | ((unsigned)o8[5] << 16);
  q.w = (unsigned)o8[6] | ((unsigned)o8[7] << 16);
  *(uint4*)(Acat + (size_t)row * KPAD + mat * KSLOT + t * 8) = q;
}

// ---------------------------------------------------------------------------
// Kernel 2: 256x256 bf16 MFMA GEMM, BK=64, 8 waves (2M x 4N), 128x64/wave.
// MINIMAL-SYNC: ONE s_barrier + ONE counted vmcnt(4) per K-tile (vs 4-8
// barriers in R2-R6; m233: stage+vmcnt+barrier dominates phase time).
// A TRIPLE-buffered (3x32KB, lookahead 2 -> A wait covers ~2000cy HBM),
// B DOUBLE-buffered (2x32KB, L2-resident panel) = 160 KB LDS exactly.
// Per tile: read kk0 (12 b128) | stage B(t+1) | 32 MFMA | read kk1 |
// stage A(t+2) | 32 MFMA | vmcnt(4) | barrier | sched_barrier(0).
// Race-free: each wave's ds_reads are lgkm-drained before its MFMAs hence
// before the tile barrier; all stage targets >=2 buffers from live readers.
// Swizzle: C_phys = C_log ^ ((row^(row>>3))&7) on 16B chunks of 128B rows
// (8-touch/bank minimal), same involution pre-applied to global source.
// grid 256 (= 32 bm x 8 bn), block 512.
// ---------------------------------------------------------------------------
__global__ __launch_bounds__(512, 2) void gemm_kernel(
    const unsigned short* __restrict__ A,   // [8192][6144] bf16
    const unsigned short* __restrict__ W,   // [2048][6144] bf16
    const float* __restrict__ fb, const float* __restrict__ bb,
    const float* __restrict__ lb,
    const float* __restrict__ selfact,      // [8192][2000] f32
    float* __restrict__ out) {              // [8192][2000] f32
  // A bufs: 3 x [256][64] bf16 at short-offset 0, 16384, 32768
  // B bufs: 2 x [256][64] bf16 at short-offset 49152, 65536
  __shared__ unsigned short ldsS[81920];    // 160 KiB

  const int tid  = threadIdx.x;
  const int wave = tid >> 6;
  const int lane = tid & 63;
  const int wm = wave >> 2;     // 0..1
  const int wn = wave & 3;      // 0..3

  // XCD-aware block swizzle (256 blocks, 8 XCDs, 32/XCD, 4 bm-panels each)
  const int nbid = (blockIdx.x & 7) * 32 + (blockIdx.x >> 3);
  const int bm = nbid >> 3;     // 0..31
  const int bn = nbid & 7;      // 0..7

  // ---- staging source pointers (inverse swizzle), 4 gload calls/matrix ----
  const unsigned short* Ap[4];
  const unsigned short* Bp[4];
#pragma unroll
  for (int c = 0; c < 4; ++c) {
    const int p = c * 512 + tid;          // linear 16B slot in 32KB buffer
    const int srow = p >> 3;              // 0..255
    const int cph = p & 7;                // physical chunk
    const int key = (srow ^ (srow >> 3)) & 7;
    const int clog = cph ^ key;           // logical chunk (K position)
    Ap[c] = A + (size_t)(bm * 256 + srow) * KPAD + clog * 8;
    Bp[c] = W + (size_t)(bn * 256 + srow) * KPAD + clog * 8;
  }

  // ---- fragment read offsets (shorts), swizzle folded per-lane ----
  int offAs[8], offBs[4];
#pragma unroll
  for (int fm = 0; fm < 8; ++fm) {
    const int row = wm * 128 + fm * 16 + (lane & 15);
    const int key = (row ^ (row >> 3)) & 7;
    offAs[fm] = (row * 128 + (((lane >> 4) ^ key) << 4)) >> 1;
  }
#pragma unroll
  for (int fn = 0; fn < 4; ++fn) {
    const int row = wn * 64 + fn * 16 + (lane & 15);
    const int key = (row ^ (row >> 3)) & 7;
    offBs[fn] = (row * 128 + (((lane >> 4) ^ key) << 4)) >> 1;
  }

  f32x4 acc[8][4] = {};
  bf16x8 afr[8], bfr[4];

#define STAGE_A(qq, tt) { \
    _Pragma("unroll") for (int c = 0; c < 4; ++c) \
      gload_lds16(Ap[c] + (size_t)(tt) * 64, \
                  &ldsS[(qq) * 16384 + c * 4096 + wave * 512]); }
#define STAGE_B(rr, tt) { \
    _Pragma("unroll") for (int c = 0; c < 4; ++c) \
      gload_lds16(Bp[c] + (size_t)(tt) * 64, \
                  &ldsS[49152 + (rr) * 16384 + c * 4096 + wave * 512]); }

#define READ_PH(qq, rr, kk) \
    _Pragma("unroll") for (int fm = 0; fm < 8; ++fm) \
      afr[fm] = *(const bf16x8*)&ldsS[(qq) * 16384 + (offAs[fm] ^ ((kk) << 5))]; \
    _Pragma("unroll") for (int fn = 0; fn < 4; ++fn) \
      bfr[fn] = *(const bf16x8*)&ldsS[49152 + (rr) * 16384 + (offBs[fn] ^ ((kk) << 5))];

#define MFMA32 { \
    __builtin_amdgcn_s_setprio(1); \
    _Pragma("unroll") for (int fm = 0; fm < 8; ++fm) \
    _Pragma("unroll") for (int fn = 0; fn < 4; ++fn) \
      acc[fm][fn] = __builtin_amdgcn_mfma_f32_16x16x32_bf16( \
          afr[fm], bfr[fn], acc[fm][fn], 0, 0, 0); \
    __builtin_amdgcn_s_setprio(0); \
  }

  // Prologue: stage A0,B0,A1,B1 (16 gloads); force A0+B0; publish.
  STAGE_A(0, 0)
  STAGE_B(0, 0)
  STAGE_A(1, 1)
  STAGE_B(1, 1)
  asm volatile("s_waitcnt vmcnt(8)" ::: "memory");
  __builtin_amdgcn_s_barrier();
  __builtin_amdgcn_sched_barrier(0);

  for (int t = 0; t < NT; ++t) {
    const int q = t % 3;
    const int r = t & 1;
    // ---- kk0 half: 12 ds_reads, stage B(t+1), 32 MFMA ----
    READ_PH(q, r, 0)
    if (t >= 1 && t + 1 < NT) STAGE_B(r ^ 1, t + 1)
    MFMA32
    // ---- kk1 half: 12 ds_reads, stage A(t+2), 32 MFMA ----
    READ_PH(q, r, 1)
    if (t + 2 < NT) STAGE_A((t + 2) % 3, t + 2)
    MFMA32
    // ---- single publication point per tile ----
    if (t < NT - 2) {
      asm volatile("s_waitcnt vmcnt(4)" ::: "memory");  // forces A(t+1)+B(t+1)
    } else {
      asm volatile("s_waitcnt vmcnt(0)" ::: "memory");
    }
    __builtin_amdgcn_s_barrier();
    __builtin_amdgcn_sched_barrier(0);
  }

  // Epilogue: C/D layout col=lane&15, row=(lane>>4)*4+reg
  const int colLane = lane & 15;
  const int rowGrp  = (lane >> 4) * 4;
#pragma unroll
  for (int fn = 0; fn < 4; ++fn) {
    const int col = bn * 256 + wn * 64 + fn * 16 + colLane;
    if (col < NREAL) {
      const float bias = fb[col] + bb[col] + lb[col];
#pragma unroll
      for (int fm = 0; fm < 8; ++fm) {
        const int row0 = bm * 256 + wm * 128 + fm * 16 + rowGrp;
#pragma unroll
        for (int rr = 0; rr < 4; ++rr) {
          const float pre = acc[fm][fn][rr] + bias;
          const size_t oi = (size_t)(row0 + rr) * NREAL + col;
          out[oi] = 0.7f * fmaxf(pre, 0.f) + 0.3f * selfact[oi];
        }
      }
    }
  }
#undef MFMA32
#undef READ_PH
#undef STAGE_B
#undef STAGE_A
}

// ---------------------------------------------------------------------------
extern "C" void kernel_launch(void* const* d_in, const int* in_sizes, int n_in,
                              void* d_out, int out_size, void* d_ws,
                              size_t ws_size, hipStream_t stream) {
  const float* prev = (const float*)d_in[0];
  const float* selfa = (const float*)d_in[1];
  const float* nxt  = (const float*)d_in[2];
  const float* fW = (const float*)d_in[3];
  const float* fb = (const float*)d_in[4];
  const float* bW = (const float*)d_in[5];
  const float* bb = (const float*)d_in[6];
  const float* lW = (const float*)d_in[7];
  const float* lb = (const float*)d_in[8];
  float* out = (float*)d_out;

  unsigned short* Acat = (unsigned short*)d_ws;                 // 100.7 MB
  unsigned short* Wcat = Acat + (size_t)BATCH * KPAD;           // +25.2 MB

  pack_kernel<<<dim3(BATCH + NPAD, 3), 256, 0, stream>>>(
      prev, nxt, selfa, fW, bW, lW, Acat, Wcat);
  gemm_kernel<<<dim3(32 * 8), 512, 0, stream>>>(Acat, Wcat, fb, bb, lb,
                                                selfa, out);
}

// Round 9
// 254.220 us; speedup vs baseline: 1.1667x; 1.0330x over previous
//
#include <hip/hip_runtime.h>
#include <hip/hip_bf16.h>

// Sizes
constexpr int BATCH = 8192;
constexpr int NREAL = 2000;   // real feature / output-col count
constexpr int KSLOT = 2048;   // per-matrix padded K slot
constexpr int KPAD  = 6144;   // 3 * 2048
constexpr int NPAD  = 2048;   // padded N (W_cat rows)
constexpr int NT    = KPAD / 64;  // 96 K-tiles of 64

typedef short bf16x8 __attribute__((ext_vector_type(8)));
typedef float f32x4  __attribute__((ext_vector_type(4)));

__device__ inline void gload_lds16(const void* g, void* l) {
  __builtin_amdgcn_global_load_lds(
      (const __attribute__((address_space(1))) unsigned int*)g,
      (__attribute__((address_space(3))) unsigned int*)l,
      16, 0, 0);
}

__device__ inline unsigned short f2bf(float x) {
  union { float f; unsigned int u; } v;
  v.f = x;
  unsigned int r = v.u + 0x7fffu + ((v.u >> 16) & 1u);
  return (unsigned short)(r >> 16);
}

// ---------------------------------------------------------------------------
// Kernel 1: fused pack. blockIdx.x < 8192: standardize (ddof=1) activations
// into A_cat [8192][6144]; else weight-concat rows into W_cat [2048][6144].
// grid (8192+2048, 3), block 256.
// ---------------------------------------------------------------------------
__global__ __launch_bounds__(256) void pack_kernel(
    const float* __restrict__ prev, const float* __restrict__ nxt,
    const float* __restrict__ selfa,
    const float* __restrict__ fW, const float* __restrict__ bW,
    const float* __restrict__ lW,
    unsigned short* __restrict__ Acat, unsigned short* __restrict__ Wcat) {
  const int mat = blockIdx.y;
  const int t = threadIdx.x;

  if (blockIdx.x >= BATCH) {
    // ---- weight pack ----
    const int s = blockIdx.x - BATCH;
    uint4 q = make_uint4(0, 0, 0, 0);
    if (s < NREAL && t < 250) {
      const float* src = ((mat == 0) ? fW : (mat == 1) ? bW : lW) +
                         (size_t)s * NREAL + t * 8;
      const float4* p = (const float4*)src;
      float4 a = p[0], b = p[1];
      q.x = (unsigned)f2bf(a.x) | ((unsigned)f2bf(a.y) << 16);
      q.y = (unsigned)f2bf(a.z) | ((unsigned)f2bf(a.w) << 16);
      q.z = (unsigned)f2bf(b.x) | ((unsigned)f2bf(b.y) << 16);
      q.w = (unsigned)f2bf(b.z) | ((unsigned)f2bf(b.w) << 16);
    }
    *(uint4*)(Wcat + (size_t)s * KPAD + mat * KSLOT + t * 8) = q;
    return;
  }

  // ---- standardize pack ----
  __shared__ float red[4];
  const int row = blockIdx.x;
  const float* src = (mat == 0) ? prev : (mat == 1) ? nxt : selfa;

  float x[8];
  float s1 = 0.f;
  if (t < 250) {
    const float4* p = (const float4*)(src + (size_t)row * NREAL + t * 8);
    float4 a = p[0], b = p[1];
    x[0] = a.x; x[1] = a.y; x[2] = a.z; x[3] = a.w;
    x[4] = b.x; x[5] = b.y; x[6] = b.z; x[7] = b.w;
#pragma unroll
    for (int j = 0; j < 8; ++j) s1 += x[j];
  } else {
#pragma unroll
    for (int j = 0; j < 8; ++j) x[j] = 0.f;
  }
#pragma unroll
  for (int o = 32; o; o >>= 1) s1 += __shfl_xor(s1, o);
  if ((t & 63) == 0) red[t >> 6] = s1;
  __syncthreads();
  const float mean = (red[0] + red[1] + red[2] + red[3]) * (1.f / 2000.f);
  __syncthreads();

  float ss = 0.f;
  if (t < 250) {
#pragma unroll
    for (int j = 0; j < 8; ++j) { float d = x[j] - mean; ss += d * d; }
  }
#pragma unroll
  for (int o = 32; o; o >>= 1) ss += __shfl_xor(ss, o);
  if ((t & 63) == 0) red[t >> 6] = ss;
  __syncthreads();
  const float var = (red[0] + red[1] + red[2] + red[3]) * (1.f / 1999.f);
  const float scale = 1.f / (sqrtf(var) + 1e-8f);

  unsigned short o8[8];
  if (t < 250) {
#pragma unroll
    for (int j = 0; j < 8; ++j) o8[j] = f2bf((x[j] - mean) * scale);
  } else {
#pragma unroll
    for (int j = 0; j < 8; ++j) o8[j] = 0;
  }
  uint4 q;
  q.x = (unsigned)o8[0] | ((unsigned)o8[1] << 16);
  q.y = (unsigned)o8[2] | ((unsigned)o8[3] << 16);
  q.z = (unsigned)o8[4] | ((unsigned)o8[5] << 16);
  q.w = (unsigned)o8[6] | ((unsigned)o8[7] << 16);
  *(uint4*)(Acat + (size_t)row * KPAD + mat * KSLOT + t * 8) = q;
}

// ---------------------------------------------------------------------------
// Kernel 2: faithful m201-style 8-phase GEMM. 256x256, BK=64, 8 waves
// (2M x 4N), 128x64/wave. Per phase: {4 af ds_reads (+8 bf at ph0) ->
// stage one row-half (2 gloads) -> [lgkmcnt(8) at ph0] -> barrier ->
// lgkmcnt(0) -> setprio(1) -> 16 MFMA (32-row quadrant x K=64) ->
// setprio(0) -> [vmcnt gate at ph3 only] -> barrier}. B read ONCE per
// tile (lives in 32 VGPR). Stage plan: A(t+1) at ph0/ph1, B(t+2) at
// ph2/ph3 -> per-wave FIFO at gate = [B(t+1)x4, A(t+1)x4, B(t+2)x4];
// vmcnt(4) forces exactly tile t+1's data (issued 2-5 phases back).
// No sched_barrier in loop. LDS [buf][mat][kq][256][32], proven XOR
// swizzle (0 conflicts R2-R6). grid 256 (= 32 bm x 8 bn), block 512.
// ---------------------------------------------------------------------------
__global__ __launch_bounds__(512, 2) void gemm_kernel(
    const unsigned short* __restrict__ A,   // [8192][6144] bf16
    const unsigned short* __restrict__ W,   // [2048][6144] bf16
    const float* __restrict__ fb, const float* __restrict__ bb,
    const float* __restrict__ lb,
    const float* __restrict__ selfact,      // [8192][2000] f32
    float* __restrict__ out) {              // [8192][2000] f32
  __shared__ unsigned short ldsS[2][2][2][256][32];  // 128 KiB
  unsigned short* ldsF = &ldsS[0][0][0][0][0];

  const int tid  = threadIdx.x;
  const int wave = tid >> 6;
  const int lane = tid & 63;
  const int wm = wave >> 2;     // 0..1
  const int wn = wave & 3;      // 0..3

  // XCD-aware block swizzle (256 blocks, 8 XCDs, 32/XCD, 4 bm-panels each)
  const int nbid = (blockIdx.x & 7) * 32 + (blockIdx.x >> 3);
  const int bm = nbid >> 3;     // 0..31
  const int bn = nbid & 7;      // 0..7

  // staging per-thread source (inverse swizzle): srow=tid>>2 (0..127 within
  // a row-half), chunk sc = (tid&3) ^ ((srow>>1)&3)
  const int srow = tid >> 2;
  const int sc = (tid & 3) ^ ((tid >> 3) & 3);
  const unsigned short* Asrc =
      A + (size_t)(bm * 256 + srow) * KPAD + sc * 8;
  const unsigned short* Bsrc =
      W + (size_t)(bn * 256 + srow) * KPAD + sc * 8;

  // fragment read bases (swizzle folds to per-lane constant)
  const int pcx = (lane >> 4) ^ ((lane >> 1) & 3);
  const unsigned short* aF = ldsF + (wm * 128 + (lane & 15)) * 32 + pcx * 8;
  const unsigned short* bF = ldsF + (wn * 64 + (lane & 15)) * 32 + pcx * 8;

  f32x4 acc[8][4] = {};
  bf16x8 bfr[4][2];

  // stage one kk-quarter of one row-half: (buf, mat, kq, rh) of tile tt
#define STQ(bu, mat, kq, rh, tt) { \
    const unsigned short* g_ = ((mat) ? Bsrc : Asrc) + \
        (size_t)(rh) * 128 * KPAD + (size_t)(tt) * 64 + (kq) * 32; \
    unsigned short* d_ = ldsF + ((bu) * 4 + (mat) * 2 + (kq)) * 8192 + \
        (rh) * 4096 + wave * 512; \
    gload_lds16(g_, d_); \
  }

#define READ_BF(bu) \
    _Pragma("unroll") for (int fn = 0; fn < 4; ++fn) \
    _Pragma("unroll") for (int kk = 0; kk < 2; ++kk) \
      bfr[fn][kk] = *(const bf16x8*)(bF + ((bu) * 4 + 2 + kk) * 8192 + fn * 512);

  // one phase: quadrant p (rows 2p*16..2p*16+31 of the wave's half)
#define PHASE(bu, p, STG, GATE) { \
    bf16x8 a00 = *(const bf16x8*)(aF + ((bu) * 4 + 0) * 8192 + (2 * (p)) * 512); \
    bf16x8 a01 = *(const bf16x8*)(aF + ((bu) * 4 + 1) * 8192 + (2 * (p)) * 512); \
    bf16x8 a10 = *(const bf16x8*)(aF + ((bu) * 4 + 0) * 8192 + (2 * (p) + 1) * 512); \
    bf16x8 a11 = *(const bf16x8*)(aF + ((bu) * 4 + 1) * 8192 + (2 * (p) + 1) * 512); \
    if ((p) == 0) { READ_BF(bu) } \
    STG \
    if ((p) == 0) asm volatile("s_waitcnt lgkmcnt(8)" ::: "memory"); \
    __builtin_amdgcn_s_barrier(); \
    asm volatile("s_waitcnt lgkmcnt(0)" ::: "memory"); \
    __builtin_amdgcn_s_setprio(1); \
    _Pragma("unroll") for (int fn = 0; fn < 4; ++fn) { \
      acc[2 * (p)][fn] = __builtin_amdgcn_mfma_f32_16x16x32_bf16( \
          a00, bfr[fn][0], acc[2 * (p)][fn], 0, 0, 0); \
      acc[2 * (p)][fn] = __builtin_amdgcn_mfma_f32_16x16x32_bf16( \
          a01, bfr[fn][1], acc[2 * (p)][fn], 0, 0, 0); \
      acc[2 * (p) + 1][fn] = __builtin_amdgcn_mfma_f32_16x16x32_bf16( \
          a10, bfr[fn][0], acc[2 * (p) + 1][fn], 0, 0, 0); \
      acc[2 * (p) + 1][fn] = __builtin_amdgcn_mfma_f32_16x16x32_bf16( \
          a11, bfr[fn][1], acc[2 * (p) + 1][fn], 0, 0, 0); \
    } \
    __builtin_amdgcn_s_setprio(0); \
    GATE \
    __builtin_amdgcn_s_barrier(); \
  }

  // TILE(t, bu): SA = stage A(t+1), SB = stage B(t+2), gate string at ph3
#define TILE(bu, t, SA, SB, GATE) { \
    PHASE(bu, 0, if (SA) { STQ((bu) ^ 1, 0, 0, 0, (t) + 1) STQ((bu) ^ 1, 0, 1, 0, (t) + 1) }, ) \
    PHASE(bu, 1, if (SA) { STQ((bu) ^ 1, 0, 0, 1, (t) + 1) STQ((bu) ^ 1, 0, 1, 1, (t) + 1) }, ) \
    PHASE(bu, 2, if (SB) { STQ((bu), 1, 0, 0, (t) + 2) STQ((bu), 1, 1, 0, (t) + 2) }, ) \
    PHASE(bu, 3, if (SB) { STQ((bu), 1, 0, 1, (t) + 2) STQ((bu), 1, 1, 1, (t) + 2) }, GATE) \
  }

  // Prologue: A(0), B(0) -> buf0; B(1) -> buf1. 12 loads/wave.
  STQ(0, 0, 0, 0, 0) STQ(0, 0, 1, 0, 0)   // A0 rh0
  STQ(0, 0, 0, 1, 0) STQ(0, 0, 1, 1, 0)   // A0 rh1
  STQ(0, 1, 0, 0, 0) STQ(0, 1, 1, 0, 0)   // B0 rh0
  STQ(0, 1, 0, 1, 0) STQ(0, 1, 1, 1, 0)   // B0 rh1
  STQ(1, 1, 0, 0, 1) STQ(1, 1, 1, 0, 1)   // B1 rh0
  STQ(1, 1, 0, 1, 1) STQ(1, 1, 1, 1, 1)   // B1 rh1
  asm volatile("s_waitcnt vmcnt(4)" ::: "memory");   // A0+B0 landed
  __builtin_amdgcn_s_barrier();

  for (int i = 0; i < 47; ++i) {
    const int t = 2 * i;
    TILE(0, t, true, true,
         asm volatile("s_waitcnt vmcnt(4)" ::: "memory");)
    TILE(1, t + 1, true, true,
         asm volatile("s_waitcnt vmcnt(4)" ::: "memory");)
  }
  // t = 94: stage A(95) only; drain all (forces A95+B95).
  TILE(0, 94, true, false,
       asm volatile("s_waitcnt vmcnt(0)" ::: "memory");)
  // t = 95: nothing staged, no gate.
  TILE(1, 95, false, false, )

  // Epilogue: C/D layout col=lane&15, row=(lane>>4)*4+reg
  const int colLane = lane & 15;
  const int rowGrp  = (lane >> 4) * 4;
#pragma unroll
  for (int fn = 0; fn < 4; ++fn) {
    const int col = bn * 256 + wn * 64 + fn * 16 + colLane;
    if (col < NREAL) {
      const float bias = fb[col] + bb[col] + lb[col];
#pragma unroll
      for (int fm = 0; fm < 8; ++fm) {
        const int row0 = bm * 256 + wm * 128 + fm * 16 + rowGrp;
#pragma unroll
        for (int r = 0; r < 4; ++r) {
          const float pre = acc[fm][fn][r] + bias;
          const size_t oi = (size_t)(row0 + r) * NREAL + col;
          out[oi] = 0.7f * fmaxf(pre, 0.f) + 0.3f * selfact[oi];
        }
      }
    }
  }
#undef TILE
#undef PHASE
#undef READ_BF
#undef STQ
}

// ---------------------------------------------------------------------------
extern "C" void kernel_launch(void* const* d_in, const int* in_sizes, int n_in,
                              void* d_out, int out_size, void* d_ws,
                              size_t ws_size, hipStream_t stream) {
  const float* prev = (const float*)d_in[0];
  const float* selfa = (const float*)d_in[1];
  const float* nxt  = (const float*)d_in[2];
  const float* fW = (const float*)d_in[3];
  const float* fb = (const float*)d_in[4];
  const float* bW = (const float*)d_in[5];
  const float* bb = (const float*)d_in[6];
  const float* lW = (const float*)d_in[7];
  const float* lb = (const float*)d_in[8];
  float* out = (float*)d_out;

  unsigned short* Acat = (unsigned short*)d_ws;                 // 100.7 MB
  unsigned short* Wcat = Acat + (size_t)BATCH * KPAD;           // +25.2 MB

  pack_kernel<<<dim3(BATCH + NPAD, 3), 256, 0, stream>>>(
      prev, nxt, selfa, fW, bW, lW, Acat, Wcat);
  gemm_kernel<<<dim3(32 * 8), 512, 0, stream>>>(Acat, Wcat, fb, bb, lb,
                                                selfa, out);
}